// Round 5
// baseline (380.406 us; speedup 1.0000x reference)
//
#include <hip/hip_runtime.h>

typedef __bf16 bf16_t;
typedef __bf16 bf16x8 __attribute__((ext_vector_type(8)));
typedef float f32x4 __attribute__((ext_vector_type(4)));

#define B_SZ 4
#define NHEADS 16
#define L_SEQ 1365
#define LP_V 1408                         // padded leading dim of transposed V (16B-aligned rows)
#define C_DIM 1024
#define HD 64
#define M_ROWS (B_SZ * L_SEQ)            // 5460
#define K_DIM 1024
#define BHL (B_SZ * NHEADS * L_SEQ)      // 87360

#define NSPLIT 33                        // q-groups 10..42 get kv-split
#define NCHUNK 3                         // kv chunks per split group (8,8,6 tiles)
#define UPB (10 + NSPLIT * NCHUNK)       // 109 work units per bh
#define NUNITS (64 * UPB)                // 6976 waves -> 1744 blocks

__device__ __forceinline__ f32x4 zero4() {
    f32x4 z; z[0] = 0.f; z[1] = 0.f; z[2] = 0.f; z[3] = 0.f; return z;
}

// async global->LDS, 16 bytes per lane. LDS dest must be wave-uniform base + lane*16.
__device__ __forceinline__ void gload_lds16(const void* g, void* l) {
    __builtin_amdgcn_global_load_lds(
        (const __attribute__((address_space(1))) void*)(uintptr_t)g,
        (__attribute__((address_space(3))) void*)(unsigned int)(uintptr_t)l,
        16, 0, 0);
}

__device__ __forceinline__ int vislen(int row) {
    // block-causal visible length; cum([1,4,16,64,256,1024]) = [1,5,21,85,341,1365]
    if (row < 1) return 1;
    if (row < 5) return 5;
    if (row < 21) return 21;
    if (row < 85) return 85;
    if (row < 341) return 341;
    return 1365;
}

// ---------------- Kernel 0: fp32 -> bf16 convert (8 elems/thread)
__global__ __launch_bounds__(256) void cvt_bf16(const float* __restrict__ in,
                                                bf16_t* __restrict__ out, int n8) {
    int i = blockIdx.x * 256 + threadIdx.x;
    if (i >= n8) return;
    const float* p = in + (size_t)i * 8;
    f32x4 a = *(const f32x4*)p;
    f32x4 b = *(const f32x4*)(p + 4);
    bf16x8 r;
    r[0] = (bf16_t)a[0]; r[1] = (bf16_t)a[1]; r[2] = (bf16_t)a[2]; r[3] = (bf16_t)a[3];
    r[4] = (bf16_t)b[0]; r[5] = (bf16_t)b[1]; r[6] = (bf16_t)b[2]; r[7] = (bf16_t)b[3];
    *(bf16x8*)(out + (size_t)i * 8) = r;
}

// ---------------- Kernel 1: QKV GEMM (128x128 tile, global_load_lds staging)
__global__ __launch_bounds__(256) void qkv_gemm(const bf16_t* __restrict__ A,
                                                const bf16_t* __restrict__ Bw,
                                                const float* __restrict__ qbias,
                                                const float* __restrict__ vbias,
                                                bf16_t* __restrict__ qo,
                                                bf16_t* __restrict__ ko,
                                                bf16_t* __restrict__ vo) {
    __shared__ __align__(16) bf16_t As[128 * 32];
    __shared__ __align__(16) bf16_t Bs[128 * 32];
    const int tid = threadIdx.x;
    const int w = tid >> 6, lane = tid & 63, quad = lane >> 4, l16 = lane & 15;
    const int mtile = blockIdx.x, ntile = blockIdx.y;
    const int mw = (w >> 1) * 64, nw = (w & 1) * 64;

    int ar0 = mtile * 128 + (tid >> 2); if (ar0 > M_ROWS - 1) ar0 = M_ROWS - 1;
    int ar1 = ar0 + 64;                 if (ar1 > M_ROWS - 1) ar1 = M_ROWS - 1;
    const int nr0 = ntile * 128 + (tid >> 2);
    const int cc = (tid & 3) * 8;

    f32x4 acc[4][4];
#pragma unroll
    for (int i = 0; i < 4; ++i)
#pragma unroll
        for (int j = 0; j < 4; ++j) acc[i][j] = zero4();

    for (int k0 = 0; k0 < K_DIM; k0 += 32) {
        __syncthreads();
        gload_lds16(A + (size_t)ar0 * K_DIM + k0 + cc, (char*)As + tid * 16);
        gload_lds16(A + (size_t)ar1 * K_DIM + k0 + cc, (char*)As + tid * 16 + 4096);
        gload_lds16(Bw + (size_t)nr0 * K_DIM + k0 + cc, (char*)Bs + tid * 16);
        gload_lds16(Bw + (size_t)(nr0 + 64) * K_DIM + k0 + cc, (char*)Bs + tid * 16 + 4096);
        __syncthreads();
        bf16x8 af[4], bfr[4];
#pragma unroll
        for (int mi = 0; mi < 4; ++mi)
            af[mi] = *(const bf16x8*)&As[(mw + mi * 16 + l16) * 32 + quad * 8];
#pragma unroll
        for (int ni = 0; ni < 4; ++ni)
            bfr[ni] = *(const bf16x8*)&Bs[(nw + ni * 16 + l16) * 32 + quad * 8];
#pragma unroll
        for (int mi = 0; mi < 4; ++mi)
#pragma unroll
            for (int ni = 0; ni < 4; ++ni)
                acc[mi][ni] = __builtin_amdgcn_mfma_f32_16x16x32_bf16(af[mi], bfr[ni], acc[mi][ni], 0, 0, 0);
    }

#pragma unroll
    for (int ni = 0; ni < 4; ++ni) {
        int ncol = ntile * 128 + nw + ni * 16 + l16;   // 0..3071
        int three = ncol >> 10;                        // 0=q,1=k,2=v
        int rem = ncol & 1023;                         // h*64+d
        int h = rem >> 6, d = rem & 63;
        float bias = 0.f;
        if (three == 0) bias = qbias[rem];
        else if (three == 2) bias = vbias[rem];
#pragma unroll
        for (int mi = 0; mi < 4; ++mi)
#pragma unroll
            for (int r = 0; r < 4; ++r) {
                int grow = mtile * 128 + mw + mi * 16 + quad * 4 + r;
                if (grow < M_ROWS) {
                    int b_ = grow / L_SEQ;
                    int l = grow - b_ * L_SEQ;
                    bf16_t val = (bf16_t)(acc[mi][ni][r] + bias);
                    if (three == 0)
                        qo[(((size_t)(b_ * NHEADS + h)) * L_SEQ + l) * HD + d] = val;
                    else if (three == 1)
                        ko[(((size_t)(b_ * NHEADS + h)) * L_SEQ + l) * HD + d] = val;
                    else
                        vo[(((size_t)(b_ * NHEADS + h)) * HD + d) * LP_V + l] = val;
                }
            }
    }
}

// ---------------- Kernel 2: L2-normalize + per-head scale (q) + RoPE, in place (bf16)
__global__ __launch_bounds__(256) void normrope(bf16_t* __restrict__ qb,
                                                bf16_t* __restrict__ kb,
                                                const float* __restrict__ cosb,
                                                const float* __restrict__ sinb,
                                                const float* __restrict__ sml) {
    const int tid = threadIdx.x;
    const int w = tid >> 6, lane = tid & 63;
    int vi = blockIdx.x * 4 + w;                 // 0..174719
    bool isq = vi < BHL;
    int idx = isq ? vi : (vi - BHL);
    bf16_t* buf = isq ? qb : kb;
    int bh = idx / L_SEQ;
    int l = idx - bh * L_SEQ;
    int h = bh & (NHEADS - 1);
    size_t base = (size_t)idx * HD;

    float v = (float)buf[base + lane];
    float ss = v * v;
#pragma unroll
    for (int off = 1; off < 64; off <<= 1) ss += __shfl_xor(ss, off);
    float nrm = fmaxf(sqrtf(ss), 1e-12f);
    v = v / nrm;
    if (isq) {
        float s = expf(fminf(sml[h], 4.6051702f)); // log(100)
        v *= s;
    }
    int i = lane >> 1;
    float c = cosb[l * 32 + i];
    float s2 = sinb[l * 32 + i];
    float p = __shfl_xor(v, 1);
    float r = (lane & 1) ? (s2 * p + c * v) : (c * v - s2 * p);
    buf[base + lane] = (bf16_t)r;
}

// ---------------- Kernel 3: flash attention, no-max softmax, kv-split with
// fp32 fragment-layout partials (linear combine; no atomics, no barriers)
__global__ __launch_bounds__(256) void attn(const bf16_t* __restrict__ q,
                                            const bf16_t* __restrict__ k,
                                            const bf16_t* __restrict__ v,
                                            bf16_t* __restrict__ ao,
                                            float* __restrict__ OP,   // [3][64][33][2048]
                                            float* __restrict__ LPb) {// [3][64][33][32]
    __shared__ __align__(16) bf16_t plds[4][2][16][72];   // per-wave transpose slices
    const int tid = threadIdx.x;
    const int w = tid >> 6, lane = tid & 63, quad = lane >> 4, l16 = lane & 15;

    const int id = blockIdx.x * 4 + w;       // wave work-unit id
    const int bh = id / UPB;
    const int u  = id - bh * UPB;
    int g, t0, t1, ck = 0;
    bool direct;
    if (u < 10) { g = u; t0 = 0; t1 = (u < 2) ? 2 : 6; direct = true; }
    else {
        int t = u - 10;
        int gi = t / NCHUNK;                 // 0..32
        ck = t - gi * NCHUNK;                // 0..2
        g = 10 + gi;
        t0 = ck * 8;
        t1 = (ck < 2) ? (t0 + 8) : 22;       // chunks of 8,8,6 tiles
        direct = false;
    }
    const int qbase = g * 32;

    bf16x8 aq[2][2];
#pragma unroll
    for (int h = 0; h < 2; ++h) {
        int mrow = qbase + h * 16 + l16;
        int mc = mrow < L_SEQ ? mrow : (L_SEQ - 1);
        const bf16_t* qp = q + ((size_t)bh * L_SEQ + mc) * HD + quad * 8;
        aq[h][0] = *(const bf16x8*)(qp);
        aq[h][1] = *(const bf16x8*)(qp + 32);
    }

    f32x4 o[2][4];
    float l_i[2][4];
    int visr[2][4];
#pragma unroll
    for (int h = 0; h < 2; ++h)
#pragma unroll
        for (int r = 0; r < 4; ++r) {
            o[h][r] = zero4();
            l_i[h][r] = 0.f;
            visr[h][r] = vislen(qbase + h * 16 + quad * 4 + r);
        }

    for (int kt = t0; kt < t1; ++kt) {
        const int kvb = kt * 64;
        bf16x8 kf0[4], kf1[4];
#pragma unroll
        for (int nb = 0; nb < 4; ++nb) {
            int n = kvb + nb * 16 + l16;
            int nc = n < L_SEQ ? n : (L_SEQ - 1);
            const bf16_t* kp = k + ((size_t)bh * L_SEQ + nc) * HD + quad * 8;
            kf0[nb] = *(const bf16x8*)(kp);
            kf1[nb] = *(const bf16x8*)(kp + 32);
        }
        f32x4 s[2][4];
#pragma unroll
        for (int h = 0; h < 2; ++h)
#pragma unroll
            for (int nb = 0; nb < 4; ++nb) {
                s[h][nb] = zero4();
                s[h][nb] = __builtin_amdgcn_mfma_f32_16x16x32_bf16(aq[h][0], kf0[nb], s[h][nb], 0, 0, 0);
                s[h][nb] = __builtin_amdgcn_mfma_f32_16x16x32_bf16(aq[h][1], kf1[nb], s[h][nb], 0, 0, 0);
            }

        // p = exp(s) masked (bounded logits: cos-attn, no max needed); partial row-sums
#pragma unroll
        for (int h = 0; h < 2; ++h)
#pragma unroll
            for (int nb = 0; nb < 4; ++nb) {
                int col = kvb + nb * 16 + l16;
#pragma unroll
                for (int r = 0; r < 4; ++r) {
                    float e = __expf(s[h][nb][r]);
                    float p = (col < visr[h][r]) ? e : 0.f;
                    l_i[h][r] += p;
                    plds[w][h][quad * 4 + r][nb * 16 + l16] = (bf16_t)p;
                }
            }
        bf16x8 ap[2][2];
#pragma unroll
        for (int h = 0; h < 2; ++h) {
            ap[h][0] = *(const bf16x8*)&plds[w][h][l16][quad * 8];
            ap[h][1] = *(const bf16x8*)&plds[w][h][l16][32 + quad * 8];
        }
#pragma unroll
        for (int nb = 0; nb < 4; ++nb) {
            const bf16_t* vp = v + ((size_t)bh * HD + nb * 16 + l16) * LP_V + kvb + quad * 8;
            bf16x8 v0 = *(const bf16x8*)(vp);    // pad cols have p=0, inert
            bf16x8 v1 = *(const bf16x8*)(vp + 32);
#pragma unroll
            for (int h = 0; h < 2; ++h) {
                o[h][nb] = __builtin_amdgcn_mfma_f32_16x16x32_bf16(ap[h][0], v0, o[h][nb], 0, 0, 0);
                o[h][nb] = __builtin_amdgcn_mfma_f32_16x16x32_bf16(ap[h][1], v1, o[h][nb], 0, 0, 0);
            }
        }
    }

    if (direct) {
        // reduce row-sums across the 16 column-lanes, scale, store (B, L, H*hd)
        const int b_ = bh >> 4, hh = bh & 15;
#pragma unroll
        for (int h = 0; h < 2; ++h)
#pragma unroll
            for (int r = 0; r < 4; ++r) {
                float ls = l_i[h][r];
#pragma unroll
                for (int off = 1; off < 16; off <<= 1) ls += __shfl_xor(ls, off);
                int rowq = qbase + h * 16 + quad * 4 + r;
                if (rowq < L_SEQ) {
                    float inv = 1.f / ls;
#pragma unroll
                    for (int nb = 0; nb < 4; ++nb) {
                        int d = nb * 16 + l16;
                        size_t di = ((size_t)(b_ * L_SEQ + rowq)) * C_DIM + hh * HD + d;
                        ao[di] = (bf16_t)(o[h][nb][r] * inv);
                    }
                }
            }
    } else {
        // write fp32 partials in fragment layout (coalesced dwordx4)
        const int g9 = g - 10;
        size_t ub = (((size_t)ck * 64 + bh) * NSPLIT + g9) * 2048;
#pragma unroll
        for (int h = 0; h < 2; ++h)
#pragma unroll
            for (int nb = 0; nb < 4; ++nb)
                *(f32x4*)(OP + ub + (size_t)((h * 4 + nb) * 64 + lane) * 4) = o[h][nb];
        size_t lb = (((size_t)ck * 64 + bh) * NSPLIT + g9) * 32;
#pragma unroll
        for (int h = 0; h < 2; ++h)
#pragma unroll
            for (int r = 0; r < 4; ++r) {
                float ls = l_i[h][r];
#pragma unroll
                for (int off = 1; off < 16; off <<= 1) ls += __shfl_xor(ls, off);
                if (l16 == 0) LPb[lb + h * 16 + quad * 4 + r] = ls;
            }
    }
}

// ---------------- Kernel 3b: combine kv-split partials, normalize, write ao
__global__ __launch_bounds__(256) void attn_reduce(const float* __restrict__ OP,
                                                   const float* __restrict__ LPb,
                                                   bf16_t* __restrict__ ao) {
    __shared__ float lsum[32];
    const int g9 = blockIdx.x, bh = blockIdx.y;
    const int tid = threadIdx.x;
    if (tid < 32) {
        float s = 0.f;
#pragma unroll
        for (int ck = 0; ck < NCHUNK; ++ck)
            s += LPb[(((size_t)ck * 64 + bh) * NSPLIT + g9) * 32 + tid];
        lsum[tid] = s;
    }
    __syncthreads();
    const int lane = tid & 63, p = tid >> 6;       // p = nb
    const int quad = lane >> 4, l16 = lane & 15;
    const int qbase = (g9 + 10) * 32;
    const int b_ = bh >> 4, hh = bh & 15;
    size_t ub = ((size_t)bh * NSPLIT + g9) * 2048;
#pragma unroll
    for (int h = 0; h < 2; ++h) {
        f32x4 acc = zero4();
#pragma unroll
        for (int ck = 0; ck < NCHUNK; ++ck)
            acc += *(const f32x4*)(OP + (size_t)ck * 64 * NSPLIT * 2048 + ub +
                                   (size_t)((h * 4 + p) * 64 + lane) * 4);
        int col = p * 16 + l16;
#pragma unroll
        for (int r = 0; r < 4; ++r) {
            int row = h * 16 + quad * 4 + r;
            int rowq = qbase + row;
            if (rowq < L_SEQ)
                ao[((size_t)(b_ * L_SEQ + rowq)) * C_DIM + hh * HD + col] =
                    (bf16_t)(acc[r] / lsum[row]);
        }
    }
}

// ---------------- Kernel 4: projection GEMM (128x128 tile), fp32 out + bias
__global__ __launch_bounds__(256) void proj_gemm(const bf16_t* __restrict__ A,
                                                 const bf16_t* __restrict__ Bw,
                                                 const float* __restrict__ bias,
                                                 float* __restrict__ out) {
    __shared__ __align__(16) bf16_t As[128 * 32];
    __shared__ __align__(16) bf16_t Bs[128 * 32];
    const int tid = threadIdx.x;
    const int w = tid >> 6, lane = tid & 63, quad = lane >> 4, l16 = lane & 15;
    const int mtile = blockIdx.x, ntile = blockIdx.y;
    const int mw = (w >> 1) * 64, nw = (w & 1) * 64;

    int ar0 = mtile * 128 + (tid >> 2); if (ar0 > M_ROWS - 1) ar0 = M_ROWS - 1;
    int ar1 = ar0 + 64;                 if (ar1 > M_ROWS - 1) ar1 = M_ROWS - 1;
    const int nr0 = ntile * 128 + (tid >> 2);
    const int cc = (tid & 3) * 8;

    f32x4 acc[4][4];
#pragma unroll
    for (int i = 0; i < 4; ++i)
#pragma unroll
        for (int j = 0; j < 4; ++j) acc[i][j] = zero4();

    for (int k0 = 0; k0 < K_DIM; k0 += 32) {
        __syncthreads();
        gload_lds16(A + (size_t)ar0 * K_DIM + k0 + cc, (char*)As + tid * 16);
        gload_lds16(A + (size_t)ar1 * K_DIM + k0 + cc, (char*)As + tid * 16 + 4096);
        gload_lds16(Bw + (size_t)nr0 * K_DIM + k0 + cc, (char*)Bs + tid * 16);
        gload_lds16(Bw + (size_t)(nr0 + 64) * K_DIM + k0 + cc, (char*)Bs + tid * 16 + 4096);
        __syncthreads();
        bf16x8 af[4], bfr[4];
#pragma unroll
        for (int mi = 0; mi < 4; ++mi)
            af[mi] = *(const bf16x8*)&As[(mw + mi * 16 + l16) * 32 + quad * 8];
#pragma unroll
        for (int ni = 0; ni < 4; ++ni)
            bfr[ni] = *(const bf16x8*)&Bs[(nw + ni * 16 + l16) * 32 + quad * 8];
#pragma unroll
        for (int mi = 0; mi < 4; ++mi)
#pragma unroll
            for (int ni = 0; ni < 4; ++ni)
                acc[mi][ni] = __builtin_amdgcn_mfma_f32_16x16x32_bf16(af[mi], bfr[ni], acc[mi][ni], 0, 0, 0);
    }

#pragma unroll
    for (int ni = 0; ni < 4; ++ni) {
        int ncol = ntile * 128 + nw + ni * 16 + l16;
        float bv = bias[ncol];
#pragma unroll
        for (int mi = 0; mi < 4; ++mi)
#pragma unroll
            for (int r = 0; r < 4; ++r) {
                int grow = mtile * 128 + mw + mi * 16 + quad * 4 + r;
                if (grow < M_ROWS)
                    out[(size_t)grow * C_DIM + ncol] = acc[mi][ni][r] + bv;
            }
    }
}

extern "C" void kernel_launch(void* const* d_in, const int* in_sizes, int n_in,
                              void* d_out, int out_size, void* d_ws, size_t ws_size,
                              hipStream_t stream) {
    const float* x    = (const float*)d_in[0];
    // d_in[1] = attn_bias (unused; mask computed analytically)
    const float* rc   = (const float*)d_in[2];
    const float* rs   = (const float*)d_in[3];
    const float* Wqkv = (const float*)d_in[4];
    const float* qb   = (const float*)d_in[5];
    const float* vb   = (const float*)d_in[6];
    const float* sml  = (const float*)d_in[7];
    const float* Wp   = (const float*)d_in[8];
    const float* bp   = (const float*)d_in[9];
    float* out = (float*)d_out;

    const size_t NQ   = (size_t)B_SZ * NHEADS * L_SEQ * HD;   // 5,591,040
    const size_t NVT  = (size_t)B_SZ * NHEADS * HD * LP_V;    // 5,767,168
    const size_t NX   = (size_t)M_ROWS * C_DIM;               // 5,591,040
    const size_t NWQ  = (size_t)3 * C_DIM * C_DIM;            // 3,145,728
    const size_t NWP  = (size_t)C_DIM * C_DIM;                // 1,048,576

    bf16_t* qo  = (bf16_t*)d_ws;
    bf16_t* ko  = qo + NQ;
    bf16_t* vo  = ko + NQ;
    bf16_t* xb  = vo + NVT;      // reused as ao after qkv (same size NX == NQ)
    bf16_t* ao  = xb;
    bf16_t* wqb = xb + NX;
    bf16_t* wpb = wqb + NWQ;
    float*  OPb = (float*)(wpb + NWP);                // [3][64][33][2048] fp32 partials
    float*  LPb = OPb + (size_t)NCHUNK * 64 * NSPLIT * 2048;

    dim3 blk(256);
    cvt_bf16<<<dim3((int)(NX  / 8 + 255) / 256), blk, 0, stream>>>(x,    xb,  (int)(NX  / 8));
    cvt_bf16<<<dim3((int)(NWQ / 8 + 255) / 256), blk, 0, stream>>>(Wqkv, wqb, (int)(NWQ / 8));
    cvt_bf16<<<dim3((int)(NWP / 8 + 255) / 256), blk, 0, stream>>>(Wp,   wpb, (int)(NWP / 8));
    qkv_gemm<<<dim3(43, 24), blk, 0, stream>>>(xb, wqb, qb, vb, qo, ko, vo);
    normrope<<<dim3((2 * BHL) / 4), blk, 0, stream>>>(qo, ko, rc, rs, sml);
    attn<<<dim3(NUNITS / 4), blk, 0, stream>>>(qo, ko, vo, ao, OPb, LPb);
    attn_reduce<<<dim3(NSPLIT, 64), blk, 0, stream>>>(OPb, LPb, ao);
    proj_gemm<<<dim3(43, 8), blk, 0, stream>>>(ao, wpb, bp, out);
}

// Round 6
// 351.371 us; speedup vs baseline: 1.0826x; 1.0826x over previous
//
#include <hip/hip_runtime.h>

typedef __bf16 bf16_t;
typedef __bf16 bf16x8 __attribute__((ext_vector_type(8)));
typedef float f32x4 __attribute__((ext_vector_type(4)));

#define B_SZ 4
#define NHEADS 16
#define L_SEQ 1365
#define LP_V 1408                         // padded leading dim of transposed V (16B-aligned rows)
#define C_DIM 1024
#define HD 64
#define M_ROWS (B_SZ * L_SEQ)            // 5460
#define K_DIM 1024
#define BHL (B_SZ * NHEADS * L_SEQ)      // 87360

__device__ __forceinline__ f32x4 zero4() {
    f32x4 z; z[0] = 0.f; z[1] = 0.f; z[2] = 0.f; z[3] = 0.f; return z;
}

// async global->LDS, 16 bytes per lane. LDS dest must be wave-uniform base + lane*16.
__device__ __forceinline__ void gload_lds16(const void* g, void* l) {
    __builtin_amdgcn_global_load_lds(
        (const __attribute__((address_space(1))) void*)(uintptr_t)g,
        (__attribute__((address_space(3))) void*)(unsigned int)(uintptr_t)l,
        16, 0, 0);
}

__device__ __forceinline__ int vislen(int row) {
    // block-causal visible length; cum([1,4,16,64,256,1024]) = [1,5,21,85,341,1365]
    if (row < 1) return 1;
    if (row < 5) return 5;
    if (row < 21) return 21;
    if (row < 85) return 85;
    if (row < 341) return 341;
    return 1365;
}

// ---------------- Kernel 0: fused fp32 -> bf16 convert of x, Wqkv, Wp
#define N8_X  (5591040 / 8)
#define N8_WQ (3145728 / 8)
#define N8_WP (1048576 / 8)
__global__ __launch_bounds__(256) void cvt_all(const float* __restrict__ x,
                                               const float* __restrict__ wq,
                                               const float* __restrict__ wp,
                                               bf16_t* __restrict__ xo,
                                               bf16_t* __restrict__ wqo,
                                               bf16_t* __restrict__ wpo) {
    int i = blockIdx.x * 256 + threadIdx.x;
    const float* in;
    bf16_t* out;
    if (i < N8_X) { in = x; out = xo; }
    else if (i < N8_X + N8_WQ) { i -= N8_X; in = wq; out = wqo; }
    else if (i < N8_X + N8_WQ + N8_WP) { i -= N8_X + N8_WQ; in = wp; out = wpo; }
    else return;
    const float* p = in + (size_t)i * 8;
    f32x4 a = *(const f32x4*)p;
    f32x4 b = *(const f32x4*)(p + 4);
    bf16x8 r;
    r[0] = (bf16_t)a[0]; r[1] = (bf16_t)a[1]; r[2] = (bf16_t)a[2]; r[3] = (bf16_t)a[3];
    r[4] = (bf16_t)b[0]; r[5] = (bf16_t)b[1]; r[6] = (bf16_t)b[2]; r[7] = (bf16_t)b[3];
    *(bf16x8*)(out + (size_t)i * 8) = r;
}

// ---------------- Kernel 1: QKV GEMM (128x128 tile, global_load_lds staging)
__global__ __launch_bounds__(256) void qkv_gemm(const bf16_t* __restrict__ A,
                                                const bf16_t* __restrict__ Bw,
                                                const float* __restrict__ qbias,
                                                const float* __restrict__ vbias,
                                                bf16_t* __restrict__ qo,
                                                bf16_t* __restrict__ ko,
                                                bf16_t* __restrict__ vo) {
    __shared__ __align__(16) bf16_t As[128 * 32];
    __shared__ __align__(16) bf16_t Bs[128 * 32];
    const int tid = threadIdx.x;
    const int w = tid >> 6, lane = tid & 63, quad = lane >> 4, l16 = lane & 15;
    const int mtile = blockIdx.x, ntile = blockIdx.y;
    const int mw = (w >> 1) * 64, nw = (w & 1) * 64;

    int ar0 = mtile * 128 + (tid >> 2); if (ar0 > M_ROWS - 1) ar0 = M_ROWS - 1;
    int ar1 = ar0 + 64;                 if (ar1 > M_ROWS - 1) ar1 = M_ROWS - 1;
    const int nr0 = ntile * 128 + (tid >> 2);
    const int cc = (tid & 3) * 8;

    f32x4 acc[4][4];
#pragma unroll
    for (int i = 0; i < 4; ++i)
#pragma unroll
        for (int j = 0; j < 4; ++j) acc[i][j] = zero4();

    for (int k0 = 0; k0 < K_DIM; k0 += 32) {
        __syncthreads();
        gload_lds16(A + (size_t)ar0 * K_DIM + k0 + cc, (char*)As + tid * 16);
        gload_lds16(A + (size_t)ar1 * K_DIM + k0 + cc, (char*)As + tid * 16 + 4096);
        gload_lds16(Bw + (size_t)nr0 * K_DIM + k0 + cc, (char*)Bs + tid * 16);
        gload_lds16(Bw + (size_t)(nr0 + 64) * K_DIM + k0 + cc, (char*)Bs + tid * 16 + 4096);
        __syncthreads();
        bf16x8 af[4], bfr[4];
#pragma unroll
        for (int mi = 0; mi < 4; ++mi)
            af[mi] = *(const bf16x8*)&As[(mw + mi * 16 + l16) * 32 + quad * 8];
#pragma unroll
        for (int ni = 0; ni < 4; ++ni)
            bfr[ni] = *(const bf16x8*)&Bs[(nw + ni * 16 + l16) * 32 + quad * 8];
#pragma unroll
        for (int mi = 0; mi < 4; ++mi)
#pragma unroll
            for (int ni = 0; ni < 4; ++ni)
                acc[mi][ni] = __builtin_amdgcn_mfma_f32_16x16x32_bf16(af[mi], bfr[ni], acc[mi][ni], 0, 0, 0);
    }

#pragma unroll
    for (int ni = 0; ni < 4; ++ni) {
        int ncol = ntile * 128 + nw + ni * 16 + l16;   // 0..3071
        int three = ncol >> 10;                        // 0=q,1=k,2=v
        int rem = ncol & 1023;                         // h*64+d
        int h = rem >> 6, d = rem & 63;
        float bias = 0.f;
        if (three == 0) bias = qbias[rem];
        else if (three == 2) bias = vbias[rem];
#pragma unroll
        for (int mi = 0; mi < 4; ++mi)
#pragma unroll
            for (int r = 0; r < 4; ++r) {
                int grow = mtile * 128 + mw + mi * 16 + quad * 4 + r;
                if (grow < M_ROWS) {
                    int b_ = grow / L_SEQ;
                    int l = grow - b_ * L_SEQ;
                    bf16_t val = (bf16_t)(acc[mi][ni][r] + bias);
                    if (three == 0)
                        qo[(((size_t)(b_ * NHEADS + h)) * L_SEQ + l) * HD + d] = val;
                    else if (three == 1)
                        ko[(((size_t)(b_ * NHEADS + h)) * L_SEQ + l) * HD + d] = val;
                    else
                        vo[(((size_t)(b_ * NHEADS + h)) * HD + d) * LP_V + l] = val;
                }
            }
    }
}

// ---------------- Kernel 2: L2-normalize + per-head scale (q) + RoPE, in place (bf16)
__global__ __launch_bounds__(256) void normrope(bf16_t* __restrict__ qb,
                                                bf16_t* __restrict__ kb,
                                                const float* __restrict__ cosb,
                                                const float* __restrict__ sinb,
                                                const float* __restrict__ sml) {
    const int tid = threadIdx.x;
    const int w = tid >> 6, lane = tid & 63;
    int vi = blockIdx.x * 4 + w;                 // 0..174719
    bool isq = vi < BHL;
    int idx = isq ? vi : (vi - BHL);
    bf16_t* buf = isq ? qb : kb;
    int bh = idx / L_SEQ;
    int l = idx - bh * L_SEQ;
    int h = bh & (NHEADS - 1);
    size_t base = (size_t)idx * HD;

    float v = (float)buf[base + lane];
    float ss = v * v;
#pragma unroll
    for (int off = 1; off < 64; off <<= 1) ss += __shfl_xor(ss, off);
    float nrm = fmaxf(sqrtf(ss), 1e-12f);
    v = v / nrm;
    if (isq) {
        float s = expf(fminf(sml[h], 4.6051702f)); // log(100)
        v *= s;
    }
    int i = lane >> 1;
    float c = cosb[l * 32 + i];
    float s2 = sinb[l * 32 + i];
    float p = __shfl_xor(v, 1);
    float r = (lane & 1) ? (s2 * p + c * v) : (c * v - s2 * p);
    buf[base + lane] = (bf16_t)r;
}

// ---------------- Kernel 3: flash attention, no-max softmax (cos-attn bounded logits),
// per-wave independent 32-row q-groups, no barriers, software-pipelined (unroll-2,
// K/V double-buffered: loads for tile t+1 issued during tile t's compute)
#define LOAD_K(kvb, f0, f1) do {                                              \
    _Pragma("unroll") for (int nb = 0; nb < 4; ++nb) {                        \
        int n_ = (kvb) + nb * 16 + l16;                                       \
        int nc_ = n_ < L_SEQ ? n_ : (L_SEQ - 1);                              \
        const bf16_t* kp_ = k + ((size_t)bh * L_SEQ + nc_) * HD + quad * 8;   \
        f0[nb] = *(const bf16x8*)(kp_);                                       \
        f1[nb] = *(const bf16x8*)(kp_ + 32);                                  \
    } } while (0)

#define LOAD_V(kvb, f0, f1) do {                                              \
    _Pragma("unroll") for (int nb = 0; nb < 4; ++nb) {                        \
        const bf16_t* vp_ = v + ((size_t)bh * HD + nb * 16 + l16) * LP_V + (kvb) + quad * 8; \
        f0[nb] = *(const bf16x8*)(vp_);                                       \
        f1[nb] = *(const bf16x8*)(vp_ + 32);                                  \
    } } while (0)

#define TILE_PHASE(kvb, kf0, kf1, vf0, vf1) do {                              \
    f32x4 s_[2][4];                                                           \
    _Pragma("unroll") for (int h = 0; h < 2; ++h)                             \
    _Pragma("unroll") for (int nb = 0; nb < 4; ++nb) {                        \
        s_[h][nb] = zero4();                                                  \
        s_[h][nb] = __builtin_amdgcn_mfma_f32_16x16x32_bf16(aq[h][0], kf0[nb], s_[h][nb], 0, 0, 0); \
        s_[h][nb] = __builtin_amdgcn_mfma_f32_16x16x32_bf16(aq[h][1], kf1[nb], s_[h][nb], 0, 0, 0); \
    }                                                                         \
    _Pragma("unroll") for (int h = 0; h < 2; ++h)                             \
    _Pragma("unroll") for (int nb = 0; nb < 4; ++nb) {                        \
        int col_ = (kvb) + nb * 16 + l16;                                     \
        _Pragma("unroll") for (int r = 0; r < 4; ++r) {                       \
            float e_ = __expf(s_[h][nb][r]);                                  \
            float p_ = (col_ < visr[h][r]) ? e_ : 0.f;                        \
            l_i[h][r] += p_;                                                  \
            plds[w][h][quad * 4 + r][nb * 16 + l16] = (bf16_t)p_;             \
        }                                                                     \
    }                                                                         \
    bf16x8 ap_[2][2];                                                         \
    _Pragma("unroll") for (int h = 0; h < 2; ++h) {                           \
        ap_[h][0] = *(const bf16x8*)&plds[w][h][l16][quad * 8];               \
        ap_[h][1] = *(const bf16x8*)&plds[w][h][l16][32 + quad * 8];          \
    }                                                                         \
    _Pragma("unroll") for (int nb = 0; nb < 4; ++nb)                          \
    _Pragma("unroll") for (int h = 0; h < 2; ++h) {                           \
        o[h][nb] = __builtin_amdgcn_mfma_f32_16x16x32_bf16(ap_[h][0], vf0[nb], o[h][nb], 0, 0, 0); \
        o[h][nb] = __builtin_amdgcn_mfma_f32_16x16x32_bf16(ap_[h][1], vf1[nb], o[h][nb], 0, 0, 0); \
    } } while (0)

__global__ __launch_bounds__(256, 2) void attn(const bf16_t* __restrict__ q,
                                               const bf16_t* __restrict__ k,
                                               const bf16_t* __restrict__ v,
                                               bf16_t* __restrict__ ao) {
    __shared__ __align__(16) bf16_t plds[4][2][16][72];   // per-wave transpose slices
    const int tid = threadIdx.x;
    const int w = tid >> 6, lane = tid & 63, quad = lane >> 4, l16 = lane & 15;
    const int bh = blockIdx.y;
    const int g = blockIdx.x + 11 * w;       // 32-row group; pairs light+heavy for balance
    if (g >= 43) return;                     // no barriers in kernel -> early exit safe
    const int qbase = g * 32;

    bf16x8 aq[2][2];
#pragma unroll
    for (int h = 0; h < 2; ++h) {
        int mrow = qbase + h * 16 + l16;
        int mc = mrow < L_SEQ ? mrow : (L_SEQ - 1);
        const bf16_t* qp = q + ((size_t)bh * L_SEQ + mc) * HD + quad * 8;
        aq[h][0] = *(const bf16x8*)(qp);
        aq[h][1] = *(const bf16x8*)(qp + 32);
    }

    f32x4 o[2][4];
    float l_i[2][4];
    int visr[2][4];
#pragma unroll
    for (int h = 0; h < 2; ++h)
#pragma unroll
        for (int r = 0; r < 4; ++r) {
            o[h][r] = zero4();
            l_i[h][r] = 0.f;
            visr[h][r] = vislen(qbase + h * 16 + quad * 4 + r);
        }

    int rl = qbase + 31; if (rl > L_SEQ - 1) rl = L_SEQ - 1;
    const int ntk = (vislen(rl) + 63) >> 6;  // always even: 2, 6, or 22

    bf16x8 ka0[4], ka1[4], kb0[4], kb1[4];
    bf16x8 va0[4], va1[4], vb0[4], vb1[4];
    LOAD_K(0, ka0, ka1);
    for (int kt = 0; kt < ntk; kt += 2) {
        const int kvbA = kt * 64, kvbB = kvbA + 64;
        LOAD_V(kvbA, va0, va1);
        LOAD_K(kvbB, kb0, kb1);
        TILE_PHASE(kvbA, ka0, ka1, va0, va1);
        const int nk = (kt + 2 < ntk) ? (kt + 2) * 64 : 0;   // wrap harmless
        LOAD_V(kvbB, vb0, vb1);
        LOAD_K(nk, ka0, ka1);
        TILE_PHASE(kvbB, kb0, kb1, vb0, vb1);
    }

    // epilogue: reduce row-sums across the 16 column-lanes, scale, store (B, L, H*hd)
    const int b_ = bh >> 4, hh = bh & 15;
#pragma unroll
    for (int h = 0; h < 2; ++h)
#pragma unroll
        for (int r = 0; r < 4; ++r) {
            float ls = l_i[h][r];
#pragma unroll
            for (int off = 1; off < 16; off <<= 1) ls += __shfl_xor(ls, off);
            int rowq = qbase + h * 16 + quad * 4 + r;
            if (rowq < L_SEQ) {
                float inv = 1.f / ls;
#pragma unroll
                for (int nb = 0; nb < 4; ++nb) {
                    int d = nb * 16 + l16;
                    size_t di = ((size_t)(b_ * L_SEQ + rowq)) * C_DIM + hh * HD + d;
                    ao[di] = (bf16_t)(o[h][nb][r] * inv);
                }
            }
        }
}

// ---------------- Kernel 4: projection GEMM (128x128 tile), fp32 out + bias
__global__ __launch_bounds__(256) void proj_gemm(const bf16_t* __restrict__ A,
                                                 const bf16_t* __restrict__ Bw,
                                                 const float* __restrict__ bias,
                                                 float* __restrict__ out) {
    __shared__ __align__(16) bf16_t As[128 * 32];
    __shared__ __align__(16) bf16_t Bs[128 * 32];
    const int tid = threadIdx.x;
    const int w = tid >> 6, lane = tid & 63, quad = lane >> 4, l16 = lane & 15;
    const int mtile = blockIdx.x, ntile = blockIdx.y;
    const int mw = (w >> 1) * 64, nw = (w & 1) * 64;

    int ar0 = mtile * 128 + (tid >> 2); if (ar0 > M_ROWS - 1) ar0 = M_ROWS - 1;
    int ar1 = ar0 + 64;                 if (ar1 > M_ROWS - 1) ar1 = M_ROWS - 1;
    const int nr0 = ntile * 128 + (tid >> 2);
    const int cc = (tid & 3) * 8;

    f32x4 acc[4][4];
#pragma unroll
    for (int i = 0; i < 4; ++i)
#pragma unroll
        for (int j = 0; j < 4; ++j) acc[i][j] = zero4();

    for (int k0 = 0; k0 < K_DIM; k0 += 32) {
        __syncthreads();
        gload_lds16(A + (size_t)ar0 * K_DIM + k0 + cc, (char*)As + tid * 16);
        gload_lds16(A + (size_t)ar1 * K_DIM + k0 + cc, (char*)As + tid * 16 + 4096);
        gload_lds16(Bw + (size_t)nr0 * K_DIM + k0 + cc, (char*)Bs + tid * 16);
        gload_lds16(Bw + (size_t)(nr0 + 64) * K_DIM + k0 + cc, (char*)Bs + tid * 16 + 4096);
        __syncthreads();
        bf16x8 af[4], bfr[4];
#pragma unroll
        for (int mi = 0; mi < 4; ++mi)
            af[mi] = *(const bf16x8*)&As[(mw + mi * 16 + l16) * 32 + quad * 8];
#pragma unroll
        for (int ni = 0; ni < 4; ++ni)
            bfr[ni] = *(const bf16x8*)&Bs[(nw + ni * 16 + l16) * 32 + quad * 8];
#pragma unroll
        for (int mi = 0; mi < 4; ++mi)
#pragma unroll
            for (int ni = 0; ni < 4; ++ni)
                acc[mi][ni] = __builtin_amdgcn_mfma_f32_16x16x32_bf16(af[mi], bfr[ni], acc[mi][ni], 0, 0, 0);
    }

#pragma unroll
    for (int ni = 0; ni < 4; ++ni) {
        int ncol = ntile * 128 + nw + ni * 16 + l16;
        float bv = bias[ncol];
#pragma unroll
        for (int mi = 0; mi < 4; ++mi)
#pragma unroll
            for (int r = 0; r < 4; ++r) {
                int grow = mtile * 128 + mw + mi * 16 + quad * 4 + r;
                if (grow < M_ROWS)
                    out[(size_t)grow * C_DIM + ncol] = acc[mi][ni][r] + bv;
            }
    }
}

extern "C" void kernel_launch(void* const* d_in, const int* in_sizes, int n_in,
                              void* d_out, int out_size, void* d_ws, size_t ws_size,
                              hipStream_t stream) {
    const float* x    = (const float*)d_in[0];
    // d_in[1] = attn_bias (unused; mask computed analytically)
    const float* rc   = (const float*)d_in[2];
    const float* rs   = (const float*)d_in[3];
    const float* Wqkv = (const float*)d_in[4];
    const float* qb   = (const float*)d_in[5];
    const float* vb   = (const float*)d_in[6];
    const float* sml  = (const float*)d_in[7];
    const float* Wp   = (const float*)d_in[8];
    const float* bp   = (const float*)d_in[9];
    float* out = (float*)d_out;

    const size_t NQ   = (size_t)B_SZ * NHEADS * L_SEQ * HD;   // 5,591,040
    const size_t NVT  = (size_t)B_SZ * NHEADS * HD * LP_V;    // 5,767,168
    const size_t NX   = (size_t)M_ROWS * C_DIM;               // 5,591,040
    const size_t NWQ  = (size_t)3 * C_DIM * C_DIM;            // 3,145,728
    const size_t NWP  = (size_t)C_DIM * C_DIM;                // 1,048,576

    bf16_t* qo  = (bf16_t*)d_ws;
    bf16_t* ko  = qo + NQ;
    bf16_t* vo  = ko + NQ;
    bf16_t* xb  = vo + NVT;      // reused as ao after qkv (same size NX == NQ)
    bf16_t* ao  = xb;
    bf16_t* wqb = xb + NX;
    bf16_t* wpb = wqb + NWQ;

    dim3 blk(256);
    const int ncvt = (N8_X + N8_WQ + N8_WP + 255) / 256;
    cvt_all<<<dim3(ncvt), blk, 0, stream>>>(x, Wqkv, Wp, xb, wqb, wpb);
    qkv_gemm<<<dim3(43, 24), blk, 0, stream>>>(xb, wqb, qb, vb, qo, ko, vo);
    normrope<<<dim3((2 * BHL) / 4), blk, 0, stream>>>(qo, ko, rc, rs, sml);
    attn<<<dim3(11, 64), blk, 0, stream>>>(qo, ko, vo, ao);
    proj_gemm<<<dim3(43, 8), blk, 0, stream>>>(ao, wpb, bp, out);
}

// Round 8
// 335.911 us; speedup vs baseline: 1.1325x; 1.0460x over previous
//
#include <hip/hip_runtime.h>

typedef __bf16 bf16_t;
typedef __bf16 bf16x8 __attribute__((ext_vector_type(8)));
typedef float f32x4 __attribute__((ext_vector_type(4)));

#define B_SZ 4
#define NHEADS 16
#define L_SEQ 1365
#define LP_V 1408                         // padded leading dim of transposed V (16B-aligned rows)
#define C_DIM 1024
#define HD 64
#define M_ROWS (B_SZ * L_SEQ)            // 5460
#define K_DIM 1024
#define BHL (B_SZ * NHEADS * L_SEQ)      // 87360

__device__ __forceinline__ f32x4 zero4() {
    f32x4 z; z[0] = 0.f; z[1] = 0.f; z[2] = 0.f; z[3] = 0.f; return z;
}

// async global->LDS, 16 bytes per lane. LDS dest must be wave-uniform base + lane*16.
__device__ __forceinline__ void gload_lds16(const void* g, void* l) {
    __builtin_amdgcn_global_load_lds(
        (const __attribute__((address_space(1))) void*)(uintptr_t)g,
        (__attribute__((address_space(3))) void*)(unsigned int)(uintptr_t)l,
        16, 0, 0);
}

__device__ __forceinline__ int vislen(int row) {
    // block-causal visible length; cum([1,4,16,64,256,1024]) = [1,5,21,85,341,1365]
    if (row < 1) return 1;
    if (row < 5) return 5;
    if (row < 21) return 21;
    if (row < 85) return 85;
    if (row < 341) return 341;
    return 1365;
}

// ---------------- Kernel 0: fused fp32 -> bf16 convert of x, Wqkv, Wp
#define N8_X  (5591040 / 8)
#define N8_WQ (3145728 / 8)
#define N8_WP (1048576 / 8)
__global__ __launch_bounds__(256) void cvt_all(const float* __restrict__ x,
                                               const float* __restrict__ wq,
                                               const float* __restrict__ wp,
                                               bf16_t* __restrict__ xo,
                                               bf16_t* __restrict__ wqo,
                                               bf16_t* __restrict__ wpo) {
    int i = blockIdx.x * 256 + threadIdx.x;
    const float* in;
    bf16_t* out;
    if (i < N8_X) { in = x; out = xo; }
    else if (i < N8_X + N8_WQ) { i -= N8_X; in = wq; out = wqo; }
    else if (i < N8_X + N8_WQ + N8_WP) { i -= N8_X + N8_WQ; in = wp; out = wpo; }
    else return;
    const float* p = in + (size_t)i * 8;
    f32x4 a = *(const f32x4*)p;
    f32x4 b = *(const f32x4*)(p + 4);
    bf16x8 r;
    r[0] = (bf16_t)a[0]; r[1] = (bf16_t)a[1]; r[2] = (bf16_t)a[2]; r[3] = (bf16_t)a[3];
    r[4] = (bf16_t)b[0]; r[5] = (bf16_t)b[1]; r[6] = (bf16_t)b[2]; r[7] = (bf16_t)b[3];
    *(bf16x8*)(out + (size_t)i * 8) = r;
}

// ---------------- Kernel 1: QKV GEMM (128x128 tile, global_load_lds staging)
// XCD-swizzled 1-D grid: 1032 = 8 XCD x (3 ntile x 43 mtile). All q/k/v written
// coalesced in (B,H,L,hd); V transposed later by vtrans.
__global__ __launch_bounds__(256) void qkv_gemm(const bf16_t* __restrict__ A,
                                                const bf16_t* __restrict__ Bw,
                                                const float* __restrict__ qbias,
                                                const float* __restrict__ vbias,
                                                bf16_t* __restrict__ qo,
                                                bf16_t* __restrict__ ko,
                                                bf16_t* __restrict__ vt) {
    __shared__ __align__(16) bf16_t As[128 * 32];
    __shared__ __align__(16) bf16_t Bs[128 * 32];
    const int tid = threadIdx.x;
    const int w = tid >> 6, lane = tid & 63, quad = lane >> 4, l16 = lane & 15;
    const int id = blockIdx.x;
    const int xcd = id & 7, s = id >> 3;
    const int ntile = xcd * 3 + s / 43;          // per-XCD B-slice: 3x128 cols (0.75 MB)
    const int mtile = s - (s / 43) * 43;
    const int mw = (w >> 1) * 64, nw = (w & 1) * 64;

    int ar0 = mtile * 128 + (tid >> 2); if (ar0 > M_ROWS - 1) ar0 = M_ROWS - 1;
    int ar1 = ar0 + 64;                 if (ar1 > M_ROWS - 1) ar1 = M_ROWS - 1;
    const int nr0 = ntile * 128 + (tid >> 2);
    const int cc = (tid & 3) * 8;

    f32x4 acc[4][4];
#pragma unroll
    for (int i = 0; i < 4; ++i)
#pragma unroll
        for (int j = 0; j < 4; ++j) acc[i][j] = zero4();

    for (int k0 = 0; k0 < K_DIM; k0 += 32) {
        __syncthreads();
        gload_lds16(A + (size_t)ar0 * K_DIM + k0 + cc, (char*)As + tid * 16);
        gload_lds16(A + (size_t)ar1 * K_DIM + k0 + cc, (char*)As + tid * 16 + 4096);
        gload_lds16(Bw + (size_t)nr0 * K_DIM + k0 + cc, (char*)Bs + tid * 16);
        gload_lds16(Bw + (size_t)(nr0 + 64) * K_DIM + k0 + cc, (char*)Bs + tid * 16 + 4096);
        __syncthreads();
        bf16x8 af[4], bfr[4];
#pragma unroll
        for (int mi = 0; mi < 4; ++mi)
            af[mi] = *(const bf16x8*)&As[(mw + mi * 16 + l16) * 32 + quad * 8];
#pragma unroll
        for (int ni = 0; ni < 4; ++ni)
            bfr[ni] = *(const bf16x8*)&Bs[(nw + ni * 16 + l16) * 32 + quad * 8];
#pragma unroll
        for (int mi = 0; mi < 4; ++mi)
#pragma unroll
            for (int ni = 0; ni < 4; ++ni)
                acc[mi][ni] = __builtin_amdgcn_mfma_f32_16x16x32_bf16(af[mi], bfr[ni], acc[mi][ni], 0, 0, 0);
    }

#pragma unroll
    for (int ni = 0; ni < 4; ++ni) {
        int ncol = ntile * 128 + nw + ni * 16 + l16;   // 0..3071
        int three = ncol >> 10;                        // 0=q,1=k,2=v
        int rem = ncol & 1023;                         // h*64+d
        int h = rem >> 6, d = rem & 63;
        float bias = 0.f;
        if (three == 0) bias = qbias[rem];
        else if (three == 2) bias = vbias[rem];
        bf16_t* dst = (three == 0) ? qo : ((three == 1) ? ko : vt);
#pragma unroll
        for (int mi = 0; mi < 4; ++mi)
#pragma unroll
            for (int r = 0; r < 4; ++r) {
                int grow = mtile * 128 + mw + mi * 16 + quad * 4 + r;
                if (grow < M_ROWS) {
                    int b_ = grow / L_SEQ;
                    int l = grow - b_ * L_SEQ;
                    dst[(((size_t)(b_ * NHEADS + h)) * L_SEQ + l) * HD + d] =
                        (bf16_t)(acc[mi][ni][r] + bias);
                }
            }
    }
}

// ---------------- Kernel 1b: V transpose (B,H,L,hd) -> (B,H,hd,LP_V), 64x64 LDS tiles
__global__ __launch_bounds__(256) void vtrans(const bf16_t* __restrict__ in,
                                              bf16_t* __restrict__ out) {
    __shared__ bf16_t t[64][64];
    const int lt = blockIdx.x * 64, bh = blockIdx.y;
    const int tid = threadIdx.x;
#pragma unroll
    for (int it = 0; it < 2; ++it) {                    // two passes: rows 0-31, 32-63
        const int r = (tid >> 3) + it * 32, c8 = (tid & 7) * 8;
        int l = lt + r; if (l > L_SEQ - 1) l = L_SEQ - 1;  // clamped rows -> pad, masked in attn
        bf16x8 v8 = *(const bf16x8*)(in + ((size_t)bh * L_SEQ + l) * HD + c8);
#pragma unroll
        for (int j = 0; j < 8; ++j) t[c8 + j][r] = v8[j];
    }
    __syncthreads();
#pragma unroll
    for (int it = 0; it < 2; ++it) {
        int c = tid + it * 256;                  // 0..511
        int d = c >> 3, off = (c & 7) * 8;
        bf16x8 o8 = *(const bf16x8*)&t[d][off];
        *(bf16x8*)(out + ((size_t)bh * HD + d) * LP_V + lt + off) = o8;
    }
}

// ---------------- Kernel 2: L2-normalize + per-head scale (q) + RoPE, in place (bf16)
__global__ __launch_bounds__(256) void normrope(bf16_t* __restrict__ qb,
                                                bf16_t* __restrict__ kb,
                                                const float* __restrict__ cosb,
                                                const float* __restrict__ sinb,
                                                const float* __restrict__ sml) {
    const int tid = threadIdx.x;
    const int w = tid >> 6, lane = tid & 63;
    int vi = blockIdx.x * 4 + w;                 // 0..174719
    bool isq = vi < BHL;
    int idx = isq ? vi : (vi - BHL);
    bf16_t* buf = isq ? qb : kb;
    int bh = idx / L_SEQ;
    int l = idx - bh * L_SEQ;
    int h = bh & (NHEADS - 1);
    size_t base = (size_t)idx * HD;

    float v = (float)buf[base + lane];
    float ss = v * v;
#pragma unroll
    for (int off = 1; off < 64; off <<= 1) ss += __shfl_xor(ss, off);
    float nrm = fmaxf(sqrtf(ss), 1e-12f);
    v = v / nrm;
    if (isq) {
        float s = expf(fminf(sml[h], 4.6051702f)); // log(100)
        v *= s;
    }
    int i = lane >> 1;
    float c = cosb[l * 32 + i];
    float s2 = sinb[l * 32 + i];
    float p = __shfl_xor(v, 1);
    float r = (lane & 1) ? (s2 * p + c * v) : (c * v - s2 * p);
    buf[base + lane] = (bf16_t)r;
}

// ---------------- Kernel 3: flash attention, no-max softmax (cos-attn bounded logits),
// per-wave independent 32-row q-groups, no barriers, V pre-transposed.
// XCD-swizzled 1-D grid: 704 = 8 XCD x (8 bh x 11 gblk); per-XCD K/V set 2.8 MB < L2.
__global__ __launch_bounds__(256) void attn(const bf16_t* __restrict__ q,
                                            const bf16_t* __restrict__ k,
                                            const bf16_t* __restrict__ v,
                                            bf16_t* __restrict__ ao) {
    __shared__ __align__(16) bf16_t plds[4][2][16][72];   // per-wave transpose slices
    const int tid = threadIdx.x;
    const int w = tid >> 6, lane = tid & 63, quad = lane >> 4, l16 = lane & 15;
    const int id = blockIdx.x;
    const int xcd = id & 7, s0 = id >> 3;                 // s0 in [0,88)
    const int bh = (xcd << 3) + s0 / 11;
    const int gblk = s0 - (s0 / 11) * 11;
    const int g = gblk + 11 * w;             // 32-row group; pairs light+heavy for balance
    if (g >= 43) return;                     // no barriers in kernel -> early exit safe
    const int qbase = g * 32;

    bf16x8 aq[2][2];
#pragma unroll
    for (int h = 0; h < 2; ++h) {
        int mrow = qbase + h * 16 + l16;
        int mc = mrow < L_SEQ ? mrow : (L_SEQ - 1);
        const bf16_t* qp = q + ((size_t)bh * L_SEQ + mc) * HD + quad * 8;
        aq[h][0] = *(const bf16x8*)(qp);
        aq[h][1] = *(const bf16x8*)(qp + 32);
    }

    f32x4 o[2][4];
    float l_i[2][4];
    int visr[2][4];
#pragma unroll
    for (int h = 0; h < 2; ++h)
#pragma unroll
        for (int r = 0; r < 4; ++r) {
            o[h][r] = zero4();
            l_i[h][r] = 0.f;
            visr[h][r] = vislen(qbase + h * 16 + quad * 4 + r);
        }

    int rl = qbase + 31; if (rl > L_SEQ - 1) rl = L_SEQ - 1;
    const int ntk = (vislen(rl) + 63) >> 6;

    for (int kt = 0; kt < ntk; ++kt) {
        const int kvb = kt * 64;
        bf16x8 kf0[4], kf1[4];
#pragma unroll
        for (int nb = 0; nb < 4; ++nb) {
            int n = kvb + nb * 16 + l16;
            int nc = n < L_SEQ ? n : (L_SEQ - 1);
            const bf16_t* kp = k + ((size_t)bh * L_SEQ + nc) * HD + quad * 8;
            kf0[nb] = *(const bf16x8*)(kp);
            kf1[nb] = *(const bf16x8*)(kp + 32);
        }
        f32x4 s[2][4];
#pragma unroll
        for (int h = 0; h < 2; ++h)
#pragma unroll
            for (int nb = 0; nb < 4; ++nb) {
                s[h][nb] = zero4();
                s[h][nb] = __builtin_amdgcn_mfma_f32_16x16x32_bf16(aq[h][0], kf0[nb], s[h][nb], 0, 0, 0);
                s[h][nb] = __builtin_amdgcn_mfma_f32_16x16x32_bf16(aq[h][1], kf1[nb], s[h][nb], 0, 0, 0);
            }

        // p = exp(s) masked; per-lane partial row-sums; write P^T staging (per-wave slice)
#pragma unroll
        for (int h = 0; h < 2; ++h)
#pragma unroll
            for (int nb = 0; nb < 4; ++nb) {
                int col = kvb + nb * 16 + l16;
#pragma unroll
                for (int r = 0; r < 4; ++r) {
                    float e = __expf(s[h][nb][r]);
                    float p = (col < visr[h][r]) ? e : 0.f;
                    l_i[h][r] += p;
                    plds[w][h][quad * 4 + r][nb * 16 + l16] = (bf16_t)p;
                }
            }
        bf16x8 ap[2][2];
#pragma unroll
        for (int h = 0; h < 2; ++h) {
            ap[h][0] = *(const bf16x8*)&plds[w][h][l16][quad * 8];
            ap[h][1] = *(const bf16x8*)&plds[w][h][l16][32 + quad * 8];
        }
#pragma unroll
        for (int nb = 0; nb < 4; ++nb) {
            const bf16_t* vp = v + ((size_t)bh * HD + nb * 16 + l16) * LP_V + kvb + quad * 8;
            bf16x8 v0 = *(const bf16x8*)(vp);    // pad cols have p=0, inert
            bf16x8 v1 = *(const bf16x8*)(vp + 32);
#pragma unroll
            for (int h = 0; h < 2; ++h) {
                o[h][nb] = __builtin_amdgcn_mfma_f32_16x16x32_bf16(ap[h][0], v0, o[h][nb], 0, 0, 0);
                o[h][nb] = __builtin_amdgcn_mfma_f32_16x16x32_bf16(ap[h][1], v1, o[h][nb], 0, 0, 0);
            }
        }
    }

    // epilogue: reduce row-sums across the 16 column-lanes, scale, store (B, L, H*hd)
    const int b_ = bh >> 4, hh = bh & 15;
#pragma unroll
    for (int h = 0; h < 2; ++h)
#pragma unroll
        for (int r = 0; r < 4; ++r) {
            float ls = l_i[h][r];
#pragma unroll
            for (int off = 1; off < 16; off <<= 1) ls += __shfl_xor(ls, off);
            int rowq = qbase + h * 16 + quad * 4 + r;
            if (rowq < L_SEQ) {
                float inv = 1.f / ls;
#pragma unroll
                for (int nb = 0; nb < 4; ++nb) {
                    int d = nb * 16 + l16;
                    size_t di = ((size_t)(b_ * L_SEQ + rowq)) * C_DIM + hh * HD + d;
                    ao[di] = (bf16_t)(o[h][nb][r] * inv);
                }
            }
        }
}

// ---------------- Kernel 4: projection GEMM (128x128 tile), fp32 out + bias
// XCD-swizzled 1-D grid: 344 = 8 XCD x 43 mtile (1 ntile per XCD).
__global__ __launch_bounds__(256) void proj_gemm(const bf16_t* __restrict__ A,
                                                 const bf16_t* __restrict__ Bw,
                                                 const float* __restrict__ bias,
                                                 float* __restrict__ out) {
    __shared__ __align__(16) bf16_t As[128 * 32];
    __shared__ __align__(16) bf16_t Bs[128 * 32];
    const int tid = threadIdx.x;
    const int w = tid >> 6, lane = tid & 63, quad = lane >> 4, l16 = lane & 15;
    const int id = blockIdx.x;
    const int ntile = id & 7, mtile = id >> 3;
    const int mw = (w >> 1) * 64, nw = (w & 1) * 64;

    int ar0 = mtile * 128 + (tid >> 2); if (ar0 > M_ROWS - 1) ar0 = M_ROWS - 1;
    int ar1 = ar0 + 64;                 if (ar1 > M_ROWS - 1) ar1 = M_ROWS - 1;
    const int nr0 = ntile * 128 + (tid >> 2);
    const int cc = (tid & 3) * 8;

    f32x4 acc[4][4];
#pragma unroll
    for (int i = 0; i < 4; ++i)
#pragma unroll
        for (int j = 0; j < 4; ++j) acc[i][j] = zero4();

    for (int k0 = 0; k0 < K_DIM; k0 += 32) {
        __syncthreads();
        gload_lds16(A + (size_t)ar0 * K_DIM + k0 + cc, (char*)As + tid * 16);
        gload_lds16(A + (size_t)ar1 * K_DIM + k0 + cc, (char*)As + tid * 16 + 4096);
        gload_lds16(Bw + (size_t)nr0 * K_DIM + k0 + cc, (char*)Bs + tid * 16);
        gload_lds16(Bw + (size_t)(nr0 + 64) * K_DIM + k0 + cc, (char*)Bs + tid * 16 + 4096);
        __syncthreads();
        bf16x8 af[4], bfr[4];
#pragma unroll
        for (int mi = 0; mi < 4; ++mi)
            af[mi] = *(const bf16x8*)&As[(mw + mi * 16 + l16) * 32 + quad * 8];
#pragma unroll
        for (int ni = 0; ni < 4; ++ni)
            bfr[ni] = *(const bf16x8*)&Bs[(nw + ni * 16 + l16) * 32 + quad * 8];
#pragma unroll
        for (int mi = 0; mi < 4; ++mi)
#pragma unroll
            for (int ni = 0; ni < 4; ++ni)
                acc[mi][ni] = __builtin_amdgcn_mfma_f32_16x16x32_bf16(af[mi], bfr[ni], acc[mi][ni], 0, 0, 0);
    }

#pragma unroll
    for (int ni = 0; ni < 4; ++ni) {
        int ncol = ntile * 128 + nw + ni * 16 + l16;
        float bv = bias[ncol];
#pragma unroll
        for (int mi = 0; mi < 4; ++mi)
#pragma unroll
            for (int r = 0; r < 4; ++r) {
                int grow = mtile * 128 + mw + mi * 16 + quad * 4 + r;
                if (grow < M_ROWS)
                    out[(size_t)grow * C_DIM + ncol] = acc[mi][ni][r] + bv;
            }
    }
}

extern "C" void kernel_launch(void* const* d_in, const int* in_sizes, int n_in,
                              void* d_out, int out_size, void* d_ws, size_t ws_size,
                              hipStream_t stream) {
    const float* x    = (const float*)d_in[0];
    // d_in[1] = attn_bias (unused; mask computed analytically)
    const float* rc   = (const float*)d_in[2];
    const float* rs   = (const float*)d_in[3];
    const float* Wqkv = (const float*)d_in[4];
    const float* qb   = (const float*)d_in[5];
    const float* vb   = (const float*)d_in[6];
    const float* sml  = (const float*)d_in[7];
    const float* Wp   = (const float*)d_in[8];
    const float* bp   = (const float*)d_in[9];
    float* out = (float*)d_out;

    const size_t NQ   = (size_t)B_SZ * NHEADS * L_SEQ * HD;   // 5,591,040
    const size_t NVT  = (size_t)B_SZ * NHEADS * HD * LP_V;    // 5,767,168
    const size_t NX   = (size_t)M_ROWS * C_DIM;               // 5,591,040
    const size_t NWQ  = (size_t)3 * C_DIM * C_DIM;            // 3,145,728
    const size_t NWP  = (size_t)C_DIM * C_DIM;                // 1,048,576

    bf16_t* qo   = (bf16_t*)d_ws;
    bf16_t* ko   = qo + NQ;
    bf16_t* vtmp = ko + NQ;      // V in (B,H,L,hd), coalesced from qkv
    bf16_t* vo   = vtmp + NQ;    // V^T in (B,H,hd,LP_V)
    bf16_t* xb   = vo + NVT;     // reused as ao after qkv (same size NX == NQ)
    bf16_t* ao   = xb;
    bf16_t* wqb  = xb + NX;
    bf16_t* wpb  = wqb + NWQ;

    dim3 blk(256);
    const int ncvt = (N8_X + N8_WQ + N8_WP + 255) / 256;
    cvt_all<<<dim3(ncvt), blk, 0, stream>>>(x, Wqkv, Wp, xb, wqb, wpb);
    qkv_gemm<<<dim3(1032), blk, 0, stream>>>(xb, wqb, qb, vb, qo, ko, vtmp);
    normrope<<<dim3((2 * BHL) / 4), blk, 0, stream>>>(qo, ko, rc, rs, sml);
    vtrans<<<dim3(22, 64), blk, 0, stream>>>(vtmp, vo);
    attn<<<dim3(704), blk, 0, stream>>>(qo, ko, vo, ao);
    proj_gemm<<<dim3(344), blk, 0, stream>>>(ao, wpb, bp, out);
}